// Round 2
// baseline (751.984 us; speedup 1.0000x reference)
//
#include <hip/hip_runtime.h>

// Quantizer: N=65536 rows, D=512, V=512 codes, fp32 in/out.
// score[n,v] = dot(x[n],w[v]) - 0.5*c[v], c[v] = sum_rows w[r][v]^2 (column sums).
// out[n,:] = w[argmax_v score] (== np argmin of -2dot+c).
// Strategy: split-bf16 MFMA (xh*wh + xl*wh + xh*wl) for approx scores + top-2;
// rows with gap < EPS_GAP get exact fp32 re-evaluation (round-1 semantics,
// which matched numpy with absmax 0).

#define DIM   512
#define VOCAB 512
#define EPS_GAP 0.5f

typedef float f32x4 __attribute__((ext_vector_type(4)));
typedef short bf16x8 __attribute__((ext_vector_type(8)));
typedef unsigned long long u64;

__device__ inline unsigned short f2bf(float f){
    unsigned u = __float_as_uint(f);
    return (unsigned short)((u + 0x7fffu + ((u >> 16) & 1u)) >> 16);  // RNE
}
__device__ inline float bf2f(unsigned short h){
    return __uint_as_float(((unsigned)h) << 16);
}
__device__ inline u64 packkey(float s, int v){
    unsigned u = __float_as_uint(s);
    u = (u & 0x80000000u) ? ~u : (u | 0x80000000u);   // orderable map
    return (((u64)u) << 32) | (unsigned)(~v);         // low word: bigger = smaller v
}
__device__ inline float keyscore(u64 k){
    unsigned e = (unsigned)(k >> 32);
    return __uint_as_float((e & 0x80000000u) ? (e & 0x7fffffffu) : ~e);
}
__device__ inline int keyv(u64 k){ return (int)(~(unsigned)(k & 0xffffffffu)); }
__device__ inline u64 umax64(u64 a, u64 b){ return a > b ? a : b; }
__device__ inline u64 umin64(u64 a, u64 b){ return a < b ? a : b; }

// ---- prep: c[v] = sum_i w[i][v]^2 (fp64 accum) ----
__global__ void colsumsq_kernel(const float* __restrict__ w, float* __restrict__ c){
    const int v = blockIdx.x * 256 + threadIdx.x;
    double s = 0.0;
    for (int i = 0; i < DIM; ++i){
        const float wv = w[i * VOCAB + v];
        s += (double)wv * (double)wv;
    }
    c[v] = (float)s;
}

// ---- prep: split w into bf16 hi/lo, pre-chunked layout ----
// element (v,k) -> [chunk=k>>5][g=(k>>3)&3][v][e=k&7]; also zeroes cnt.
__global__ void prep_w(const float* __restrict__ w,
                       unsigned short* __restrict__ whc,
                       unsigned short* __restrict__ wlc,
                       unsigned* __restrict__ cnt){
    const int i = blockIdx.x * 256 + threadIdx.x;   // 0..262143
    const float f = w[i];
    const unsigned short h = f2bf(f);
    const unsigned short l = f2bf(f - bf2f(h));
    const int v = i >> 9, k = i & 511;
    const int d = (k >> 5) * 16384 + ((k >> 3) & 3) * 4096 + v * 8 + (k & 7);
    whc[d] = h; wlc[d] = l;
    if (i == 0) *cnt = 0u;
}

// ---- k1: split-bf16 MFMA scores + per-row top-2 + flag near-ties ----
// block 256 thr = 4 waves; block tile 64 rows x 512 cols; wave = 32 rows x 256 cols.
// K-chunk 32 (one MFMA-K). LDS ~76KB -> 2 blocks/CU.
__launch_bounds__(256, 2)
__global__ void k1_scores(const float* __restrict__ x,
                          const unsigned short* __restrict__ whc,
                          const unsigned short* __restrict__ wlc,
                          const float* __restrict__ cg,
                          int* __restrict__ idx,
                          int* __restrict__ list,
                          unsigned* __restrict__ cnt){
    __shared__ __align__(16) unsigned short Bh[16384];  // [g=4][v=512][8] bf16
    __shared__ __align__(16) unsigned short Bl[16384];
    __shared__ __align__(16) unsigned short Ah[2048];   // [g=4][row=64][8]
    __shared__ __align__(16) unsigned short Al[2048];
    __shared__ u64 mergeK[64][2][2];

    const int t = threadIdx.x;
    const int lane = t & 63, wv = t >> 6, quad = lane >> 4, lm = lane & 15;
    const int colhalf = wv & 1, rowhalf = wv >> 1;
    const int cb = colhalf << 8;                 // wave col base (0 or 256)
    const long rbase = (long)blockIdx.x * 64;
    const float* xblk = x + rbase * DIM;

    // acc init = -0.5*c[col] (bias folded in; all 4 regs share the lane's col)
    f32x4 acc[2][16];
    #pragma unroll
    for (int ct = 0; ct < 16; ++ct){
        const float bias = -0.5f * cg[cb + ct * 16 + lm];
        f32x4 z; z[0] = bias; z[1] = bias; z[2] = bias; z[3] = bias;
        acc[0][ct] = z; acc[1][ct] = z;
    }

    for (int ch = 0; ch < 16; ++ch){
        __syncthreads();
        // stage B: pre-chunked, fully coalesced 16B/lane
        {
            const unsigned short* srcH = whc + ch * 16384;
            const unsigned short* srcL = wlc + ch * 16384;
            #pragma unroll
            for (int i = 0; i < 8; ++i){
                const int u = i * 256 + t;
                *(uint4*)&Bh[u * 8] = *(const uint4*)&srcH[u * 8];
                *(uint4*)&Bl[u * 8] = *(const uint4*)&srcL[u * 8];
            }
        }
        // stage A: 64 rows x 32 k fp32 -> bf16 hi/lo split
        {
            #pragma unroll
            for (int i = 0; i < 2; ++i){
                const int j = i * 256 + t;          // 0..511
                const int row = j >> 3, kq = j & 7;
                const float4 a4 = *(const float4*)(xblk + (long)row * DIM + ch * 32 + kq * 4);
                ushort4 h4, l4;
                h4.x = f2bf(a4.x); l4.x = f2bf(a4.x - bf2f(h4.x));
                h4.y = f2bf(a4.y); l4.y = f2bf(a4.y - bf2f(h4.y));
                h4.z = f2bf(a4.z); l4.z = f2bf(a4.z - bf2f(h4.z));
                h4.w = f2bf(a4.w); l4.w = f2bf(a4.w - bf2f(h4.w));
                const int d = (kq >> 1) * 512 + row * 8 + (kq & 1) * 4;
                *(ushort4*)&Ah[d] = h4;
                *(ushort4*)&Al[d] = l4;
            }
        }
        __syncthreads();

        // A frags: row = rowhalf*32 + rt*16 + lm, k-group = quad
        const int ar = rowhalf * 32 + lm;
        const bf16x8 ah0 = *(const bf16x8*)&Ah[quad * 512 + ar * 8];
        const bf16x8 al0 = *(const bf16x8*)&Al[quad * 512 + ar * 8];
        const bf16x8 ah1 = *(const bf16x8*)&Ah[quad * 512 + (ar + 16) * 8];
        const bf16x8 al1 = *(const bf16x8*)&Al[quad * 512 + (ar + 16) * 8];
        #pragma unroll
        for (int ct = 0; ct < 16; ++ct){
            const int vo = quad * 4096 + (cb + ct * 16 + lm) * 8;
            const bf16x8 bh = *(const bf16x8*)&Bh[vo];
            const bf16x8 bl = *(const bf16x8*)&Bl[vo];
            f32x4 a0 = acc[0][ct], a1 = acc[1][ct];
            a0 = __builtin_amdgcn_mfma_f32_16x16x32_bf16(ah0, bh, a0, 0, 0, 0);
            a1 = __builtin_amdgcn_mfma_f32_16x16x32_bf16(ah1, bh, a1, 0, 0, 0);
            a0 = __builtin_amdgcn_mfma_f32_16x16x32_bf16(al0, bh, a0, 0, 0, 0);
            a1 = __builtin_amdgcn_mfma_f32_16x16x32_bf16(al1, bh, a1, 0, 0, 0);
            a0 = __builtin_amdgcn_mfma_f32_16x16x32_bf16(ah0, bl, a0, 0, 0, 0);
            a1 = __builtin_amdgcn_mfma_f32_16x16x32_bf16(ah1, bl, a1, 0, 0, 0);
            acc[0][ct] = a0; acc[1][ct] = a1;
        }
    }

    // epilogue: per-lane top-2 over its 16 cols, then quad merge (16 lanes = 256 cols)
    #pragma unroll
    for (int rt = 0; rt < 2; ++rt){
        #pragma unroll
        for (int reg = 0; reg < 4; ++reg){
            u64 b1 = 0, b2 = 0;
            #pragma unroll
            for (int ct = 0; ct < 16; ++ct){
                const u64 key = packkey(acc[rt][ct][reg], cb + ct * 16 + lm);
                if (key > b1){ b2 = b1; b1 = key; }
                else if (key > b2){ b2 = key; }
            }
            #pragma unroll
            for (int m = 1; m <= 8; m <<= 1){
                const u64 o1 = __shfl_xor(b1, m, 64);
                const u64 o2 = __shfl_xor(b2, m, 64);
                const u64 n1 = umax64(b1, o1);
                b2 = umax64(umin64(b1, o1), umax64(b2, o2));
                b1 = n1;
            }
            if (lm == 0){
                const int row = rowhalf * 32 + rt * 16 + quad * 4 + reg;
                mergeK[row][colhalf][0] = b1;
                mergeK[row][colhalf][1] = b2;
            }
        }
    }
    __syncthreads();
    if (t < 64){
        const u64 a1 = mergeK[t][0][0], a2 = mergeK[t][0][1];
        const u64 c1 = mergeK[t][1][0], c2 = mergeK[t][1][1];
        const u64 f1 = umax64(a1, c1);
        const u64 f2 = umax64(umin64(a1, c1), umax64(a2, c2));
        idx[rbase + t] = keyv(f1);
        if (keyscore(f1) - keyscore(f2) < EPS_GAP){
            const unsigned p = atomicAdd(cnt, 1u);
            list[p] = (int)(rbase + t);
        }
    }
}

// ---- exact fp32 re-check for flagged (near-tie) rows ----
__global__ void refine_rows(const float* __restrict__ x, const float* __restrict__ w,
                            const float* __restrict__ cg, const int* __restrict__ list,
                            const unsigned* __restrict__ cnt, int* __restrict__ idx){
    __shared__ u64 wk[4];
    const int n = (int)*cnt;
    for (int i = blockIdx.x; i < n; i += gridDim.x){
        const int row = list[i];
        const float* xr = x + (long)row * DIM;
        u64 best = 0;
        for (int v = threadIdx.x; v < VOCAB; v += 256){
            const float* wr = w + (long)v * DIM;
            float s = 0.f;
            for (int k = 0; k < DIM; ++k) s = fmaf(xr[k], wr[k], s);
            s -= 0.5f * cg[v];
            best = umax64(best, packkey(s, v));
        }
        #pragma unroll
        for (int m = 1; m <= 32; m <<= 1) best = umax64(best, __shfl_xor(best, m, 64));
        if ((threadIdx.x & 63) == 0) wk[threadIdx.x >> 6] = best;
        __syncthreads();
        if (threadIdx.x == 0){
            const u64 b = umax64(umax64(wk[0], wk[1]), umax64(wk[2], wk[3]));
            idx[row] = keyv(b);
        }
        __syncthreads();
    }
}

// ---- gather winning rows to out ----
__global__ void gather_rows(const float* __restrict__ w, const int* __restrict__ idx,
                            float* __restrict__ out){
    const long f = ((long)blockIdx.x * 256 + threadIdx.x) << 3;  // float index, 8/thread
    const int row = (int)(f >> 9);
    const int v = idx[row];
    const float* src = w + (long)v * DIM + (int)(f & 511);
    const float4 a = *(const float4*)src;
    const float4 b = *(const float4*)(src + 4);
    *(float4*)(out + f) = a;
    *(float4*)(out + f + 4) = b;
}

// ---- fallback: round-1 fp32 kernel (self-contained, no ws) ----
__launch_bounds__(256)
__global__ void fallback_full(const float* __restrict__ x, const float* __restrict__ w,
                              float* __restrict__ out){
    __shared__ __align__(16) float As[16][68];
    __shared__ __align__(16) float Bs[16][VOCAB];
    __shared__ int   idx_s[64];
    __shared__ float c_s[VOCAB];

    const int t  = threadIdx.x;
    const int tx = t & 31;
    const int ty = t >> 5;
    const long rbase = (long)blockIdx.x * 64;
    const float* xblk = x + rbase * DIM;

    for (int vv = t; vv < VOCAB; vv += 256){
        double s = 0.0;
        for (int i = 0; i < DIM; ++i){
            const float wv = w[i * VOCAB + vv];
            s += (double)wv * (double)wv;
        }
        c_s[vv] = (float)s;
    }

    float acc[8][16];
    #pragma unroll
    for (int r = 0; r < 8; ++r)
        #pragma unroll
        for (int j = 0; j < 16; ++j) acc[r][j] = 0.0f;

    for (int k0 = 0; k0 < DIM; k0 += 16){
        __syncthreads();
        {
            const int r  = t >> 2;
            const int kq = (t & 3) << 2;
            const float4 a4 = *(const float4*)(xblk + (long)r * DIM + k0 + kq);
            As[kq + 0][r] = a4.x; As[kq + 1][r] = a4.y;
            As[kq + 2][r] = a4.z; As[kq + 3][r] = a4.w;
        }
        #pragma unroll
        for (int vb = 0; vb < 8; ++vb){
            const int v  = (t >> 2) + (vb << 6);
            const int kq = (t & 3) << 2;
            const float4 b4 = *(const float4*)(w + (long)v * DIM + k0 + kq);
            Bs[kq + 0][v] = b4.x; Bs[kq + 1][v] = b4.y;
            Bs[kq + 2][v] = b4.z; Bs[kq + 3][v] = b4.w;
        }
        __syncthreads();

        #pragma unroll
        for (int k = 0; k < 16; ++k){
            float a[8];
            const float4 a03 = *(const float4*)&As[k][ty * 8];
            const float4 a47 = *(const float4*)&As[k][ty * 8 + 4];
            a[0] = a03.x; a[1] = a03.y; a[2] = a03.z; a[3] = a03.w;
            a[4] = a47.x; a[5] = a47.y; a[6] = a47.z; a[7] = a47.w;
            float b[16];
            #pragma unroll
            for (int j = 0; j < 16; ++j) b[j] = Bs[k][tx + (j << 5)];
            #pragma unroll
            for (int r = 0; r < 8; ++r)
                #pragma unroll
                for (int j = 0; j < 16; ++j)
                    acc[r][j] = fmaf(a[r], b[j], acc[r][j]);
        }
    }

    #pragma unroll
    for (int r = 0; r < 8; ++r){
        float best = acc[r][0] - 0.5f * c_s[tx];
        int   bv   = tx;
        #pragma unroll
        for (int j = 1; j < 16; ++j){
            const float s = acc[r][j] - 0.5f * c_s[tx + (j << 5)];
            if (s > best){ best = s; bv = tx + (j << 5); }
        }
        unsigned u = __float_as_uint(best);
        u = (u & 0x80000000u) ? ~u : (u | 0x80000000u);
        u64 key = ((u64)u << 32) | (unsigned)(~(unsigned)bv);
        #pragma unroll
        for (int m = 1; m <= 16; m <<= 1){
            const u64 o = __shfl_xor(key, m, 64);
            if (o > key) key = o;
        }
        if (tx == 0) idx_s[ty * 8 + r] = (int)(~(unsigned)(key & 0xFFFFFFFFull));
    }
    __syncthreads();

    for (int rr = 0; rr < 64; rr += 2){
        const int row  = rr + (t >> 7);
        const int col  = (t & 127) << 2;
        const int vidx = idx_s[row];
        const float4 val = *(const float4*)(w + (long)vidx * DIM + col);
        *(float4*)(out + (rbase + row) * DIM + col) = val;
    }
}

extern "C" void kernel_launch(void* const* d_in, const int* in_sizes, int n_in,
                              void* d_out, int out_size, void* d_ws, size_t ws_size,
                              hipStream_t stream){
    const float* x = (const float*)d_in[0];
    const float* w = (const float*)d_in[1];
    float* out = (float*)d_out;
    const int rows = in_sizes[0] / DIM;        // 65536

    // ws layout (bytes)
    const size_t whc_off  = 0;
    const size_t wlc_off  = whc_off + (size_t)DIM * VOCAB * 2;   // 512KB
    const size_t c_off    = wlc_off + (size_t)DIM * VOCAB * 2;   // +512KB
    const size_t idx_off  = c_off   + (size_t)VOCAB * 4;
    const size_t list_off = idx_off + (size_t)rows * 4;
    const size_t cnt_off  = list_off + (size_t)rows * 4;
    const size_t need     = cnt_off + 16;

    if (ws_size >= need){
        unsigned short* whc = (unsigned short*)((char*)d_ws + whc_off);
        unsigned short* wlc = (unsigned short*)((char*)d_ws + wlc_off);
        float*    c    = (float*)((char*)d_ws + c_off);
        int*      idx  = (int*)((char*)d_ws + idx_off);
        int*      list = (int*)((char*)d_ws + list_off);
        unsigned* cnt  = (unsigned*)((char*)d_ws + cnt_off);

        prep_w<<<(DIM * VOCAB) / 256, 256, 0, stream>>>(w, whc, wlc, cnt);
        colsumsq_kernel<<<VOCAB / 256, 256, 0, stream>>>(w, c);
        k1_scores<<<rows / 64, 256, 0, stream>>>(x, whc, wlc, c, idx, list, cnt);
        refine_rows<<<256, 256, 0, stream>>>(x, w, c, list, cnt, idx);
        gather_rows<<<rows / 4, 256, 0, stream>>>(w, idx, out);
    } else {
        fallback_full<<<rows / 64, 256, 0, stream>>>(x, w, out);
    }
}

// Round 3
// 338.733 us; speedup vs baseline: 2.2200x; 2.2200x over previous
//
#include <hip/hip_runtime.h>

// Quantizer: N=65536 rows, D=512, V=512 codes, fp32 in/out.
// score[n,v] = dot(x[n],w[v]) - 0.5*c[v], c[v] = sum_rows w[r][v]^2 (column sums).
// out[n,:] = w[argmax_v score] (== np argmin of -2dot+c).
// k1: split-bf16 MFMA (xh*wh + xl*wh + xh*wl) scores + top-2 + fused gather;
// rows with top-2 gap < EPS_GAP get exact fp32 re-evaluation + rewrite.
// Split error rms ~2e-4; EPS 0.03 = ~15x worst-case -> ~300 flagged rows.

#define DIM   512
#define VOCAB 512
#define EPS_GAP 0.03f

typedef float f32x4 __attribute__((ext_vector_type(4)));
typedef short bf16x8 __attribute__((ext_vector_type(8)));
typedef unsigned long long u64;

__device__ inline unsigned short f2bf(float f){
    unsigned u = __float_as_uint(f);
    return (unsigned short)((u + 0x7fffu + ((u >> 16) & 1u)) >> 16);  // RNE
}
__device__ inline float bf2f(unsigned short h){
    return __uint_as_float(((unsigned)h) << 16);
}
__device__ inline u64 packkey(float s, int v){
    unsigned u = __float_as_uint(s);
    u = (u & 0x80000000u) ? ~u : (u | 0x80000000u);   // orderable map
    return (((u64)u) << 32) | (unsigned)(~v);         // low word: bigger = smaller v
}
__device__ inline float keyscore(u64 k){
    unsigned e = (unsigned)(k >> 32);
    return __uint_as_float((e & 0x80000000u) ? (e & 0x7fffffffu) : ~e);
}
__device__ inline int keyv(u64 k){ return (int)(~(unsigned)(k & 0xffffffffu)); }
__device__ inline u64 umax64(u64 a, u64 b){ return a > b ? a : b; }
__device__ inline u64 umin64(u64 a, u64 b){ return a < b ? a : b; }

// async global->LDS, 16B per lane; LDS dest = wave-uniform base + lane*16
__device__ inline void gload_lds16(const void* g, void* l){
    __builtin_amdgcn_global_load_lds(
        (const __attribute__((address_space(1))) unsigned*)g,
        (__attribute__((address_space(3))) unsigned*)l, 16, 0, 0);
}

// ---- prep: c[v] = sum_i w[i][v]^2 (fp64 accum), one wave per column ----
__global__ void colsumsq_kernel(const float* __restrict__ w, float* __restrict__ c){
    const int v = blockIdx.x;              // 512 blocks
    const int lane = threadIdx.x;          // 64
    double s = 0.0;
    for (int i = lane; i < DIM; i += 64){
        const float wv = w[i * VOCAB + v];
        s += (double)wv * (double)wv;
    }
    #pragma unroll
    for (int m = 1; m <= 32; m <<= 1) s += __shfl_xor(s, m, 64);
    if (lane == 0) c[v] = (float)s;
}

// ---- prep: split w into bf16 hi/lo, pre-chunked layout ----
// element (v,k) -> [chunk=k>>5][g=(k>>3)&3][v][e=k&7]; also zeroes cnt.
__global__ void prep_w(const float* __restrict__ w,
                       unsigned short* __restrict__ whc,
                       unsigned short* __restrict__ wlc,
                       unsigned* __restrict__ cnt){
    const int i = blockIdx.x * 256 + threadIdx.x;   // 0..262143
    const float f = w[i];
    const unsigned short h = f2bf(f);
    const unsigned short l = f2bf(f - bf2f(h));
    const int v = i >> 9, k = i & 511;
    const int d = (k >> 5) * 16384 + ((k >> 3) & 3) * 4096 + v * 8 + (k & 7);
    whc[d] = h; wlc[d] = l;
    if (i == 0) *cnt = 0u;
}

// ---- k1: split-bf16 MFMA scores + top-2 + flag near-ties + fused gather ----
// block 256 thr = 4 waves; block tile 64 rows x 512 cols.
// wave tile: 64 rows x 128 cols (rt=4 x ct=8, 16x16x32 MFMA, 128 acc VGPRs).
// K-chunk 32. LDS ~76KB -> 2 blocks/CU.
__launch_bounds__(256, 2)
__global__ void k1_scores(const float* __restrict__ x,
                          const unsigned short* __restrict__ whc,
                          const unsigned short* __restrict__ wlc,
                          const float* __restrict__ cg,
                          const float* __restrict__ w,
                          float* __restrict__ out,
                          int* __restrict__ list,
                          unsigned* __restrict__ cnt){
    __shared__ __align__(16) unsigned short Bh[16384];  // [g=4][v=512][8] bf16
    __shared__ __align__(16) unsigned short Bl[16384];
    __shared__ __align__(16) unsigned short Ah[2048];   // [g=4][row=64][8]
    __shared__ __align__(16) unsigned short Al[2048];
    __shared__ u64 mergeK[64][4][2];
    __shared__ int idx_s[64];

    const int t = threadIdx.x;
    const int lane = t & 63, wv = t >> 6, quad = lane >> 4, lm = lane & 15;
    const int cb = wv << 7;                 // wave col base (0,128,256,384)
    const long rbase = (long)blockIdx.x * 64;
    const float* xblk = x + rbase * DIM;

    // acc init = -0.5*c[col] (bias folded; all rows of a lane share its col)
    f32x4 acc[4][8];
    #pragma unroll
    for (int ct = 0; ct < 8; ++ct){
        const float bias = -0.5f * cg[cb + ct * 16 + lm];
        f32x4 z; z[0] = bias; z[1] = bias; z[2] = bias; z[3] = bias;
        #pragma unroll
        for (int rt = 0; rt < 4; ++rt) acc[rt][ct] = z;
    }

    for (int ch = 0; ch < 16; ++ch){
        __syncthreads();
        // stage B: async DMA, 16 x 1KB per wave (layout is flat-contiguous)
        {
            const unsigned short* srcH = whc + ch * 16384 + (wv << 12);
            const unsigned short* srcL = wlc + ch * 16384 + (wv << 12);
            #pragma unroll
            for (int i = 0; i < 8; ++i){
                gload_lds16(srcH + i * 512 + lane * 8, &Bh[(wv << 12) + i * 512]);
                gload_lds16(srcL + i * 512 + lane * 8, &Bl[(wv << 12) + i * 512]);
            }
        }
        // stage A: 64 rows x 32 k fp32 -> bf16 hi/lo split
        #pragma unroll
        for (int i = 0; i < 2; ++i){
            const int j = i * 256 + t;          // 0..511
            const int row = j >> 3, kq = j & 7;
            const float4 a4 = *(const float4*)(xblk + (long)row * DIM + ch * 32 + kq * 4);
            ushort4 h4, l4;
            h4.x = f2bf(a4.x); l4.x = f2bf(a4.x - bf2f(h4.x));
            h4.y = f2bf(a4.y); l4.y = f2bf(a4.y - bf2f(h4.y));
            h4.z = f2bf(a4.z); l4.z = f2bf(a4.z - bf2f(h4.z));
            h4.w = f2bf(a4.w); l4.w = f2bf(a4.w - bf2f(h4.w));
            const int d = (kq >> 1) * 512 + row * 8 + (kq & 1) * 4;
            *(ushort4*)&Ah[d] = h4;
            *(ushort4*)&Al[d] = l4;
        }
        __syncthreads();   // drains vmcnt -> DMA complete

        // A frags: row = rt*16 + lm, k = quad*8 + j (verified in-situ R2)
        bf16x8 ah[4], al[4];
        #pragma unroll
        for (int rt = 0; rt < 4; ++rt){
            ah[rt] = *(const bf16x8*)&Ah[quad * 512 + (rt * 16 + lm) * 8];
            al[rt] = *(const bf16x8*)&Al[quad * 512 + (rt * 16 + lm) * 8];
        }
        #pragma unroll
        for (int ct = 0; ct < 8; ++ct){
            const int vo = quad * 4096 + (cb + ct * 16 + lm) * 8;
            const bf16x8 bh = *(const bf16x8*)&Bh[vo];
            const bf16x8 bl = *(const bf16x8*)&Bl[vo];
            #pragma unroll
            for (int rt = 0; rt < 4; ++rt){
                f32x4 a = acc[rt][ct];
                a = __builtin_amdgcn_mfma_f32_16x16x32_bf16(ah[rt], bh, a, 0, 0, 0);
                a = __builtin_amdgcn_mfma_f32_16x16x32_bf16(al[rt], bh, a, 0, 0, 0);
                a = __builtin_amdgcn_mfma_f32_16x16x32_bf16(ah[rt], bl, a, 0, 0, 0);
                acc[rt][ct] = a;
            }
        }
    }

    // epilogue: per-lane top-2 over its 8 cols, lm-merge (16 lanes = 128 cols)
    #pragma unroll
    for (int rt = 0; rt < 4; ++rt){
        #pragma unroll
        for (int reg = 0; reg < 4; ++reg){
            u64 b1 = 0, b2 = 0;
            #pragma unroll
            for (int ct = 0; ct < 8; ++ct){
                const u64 key = packkey(acc[rt][ct][reg], cb + ct * 16 + lm);
                if (key > b1){ b2 = b1; b1 = key; }
                else if (key > b2){ b2 = key; }
            }
            #pragma unroll
            for (int m = 1; m <= 8; m <<= 1){
                const u64 o1 = __shfl_xor(b1, m, 64);
                const u64 o2 = __shfl_xor(b2, m, 64);
                const u64 n1 = umax64(b1, o1);
                b2 = umax64(umin64(b1, o1), umax64(b2, o2));
                b1 = n1;
            }
            if (lm == 0){
                const int row = rt * 16 + quad * 4 + reg;
                mergeK[row][wv][0] = b1;
                mergeK[row][wv][1] = b2;
            }
        }
    }
    __syncthreads();
    if (t < 64){
        u64 p1 = mergeK[t][0][0], p2 = mergeK[t][0][1];
        #pragma unroll
        for (int i = 1; i < 4; ++i){
            const u64 q1 = mergeK[t][i][0], q2 = mergeK[t][i][1];
            const u64 n1 = umax64(p1, q1);
            p2 = umax64(umin64(p1, q1), umax64(p2, q2));
            p1 = n1;
        }
        idx_s[t] = keyv(p1);
        if (keyscore(p1) - keyscore(p2) < EPS_GAP){
            const unsigned p = atomicAdd(cnt, 1u);
            list[p] = (int)(rbase + t);
        }
    }
    __syncthreads();

    // fused gather: 64 rows x 512 floats, 2 rows / iteration
    for (int rr = 0; rr < 64; rr += 2){
        const int row  = rr + (t >> 7);
        const int col  = (t & 127) << 2;
        const int vidx = idx_s[row];
        const float4 val = *(const float4*)(w + (long)vidx * DIM + col);
        *(float4*)(out + (rbase + row) * DIM + col) = val;
    }
}

// ---- exact fp32 re-check + rewrite for flagged (near-tie) rows ----
// one block per row; x in LDS; 2 codes/thread with float4 w loads (L2-hot).
__global__ void refine_rows(const float* __restrict__ x, const float* __restrict__ w,
                            const float* __restrict__ cg, const int* __restrict__ list,
                            const unsigned* __restrict__ cnt, float* __restrict__ out){
    __shared__ float xs[DIM];
    __shared__ u64 wk[4];
    __shared__ int bestv_s;
    const int t = threadIdx.x;
    const int n = (int)*cnt;
    for (int i = blockIdx.x; i < n; i += gridDim.x){
        const int row = list[i];
        __syncthreads();   // protect xs/bestv_s reuse across iterations
        if (t < 128) *(float4*)&xs[t * 4] = *(const float4*)(x + (long)row * DIM + t * 4);
        __syncthreads();
        u64 best = 0;
        #pragma unroll
        for (int vv = 0; vv < 2; ++vv){
            const int v = t + vv * 256;
            const float* wr = w + (long)v * DIM;
            float s = 0.f;
            for (int k = 0; k < DIM; k += 4){
                const float4 w4 = *(const float4*)(wr + k);
                s = fmaf(w4.x, xs[k + 0], s);
                s = fmaf(w4.y, xs[k + 1], s);
                s = fmaf(w4.z, xs[k + 2], s);
                s = fmaf(w4.w, xs[k + 3], s);
            }
            s -= 0.5f * cg[v];
            best = umax64(best, packkey(s, v));
        }
        #pragma unroll
        for (int m = 1; m <= 32; m <<= 1) best = umax64(best, __shfl_xor(best, m, 64));
        if ((t & 63) == 0) wk[t >> 6] = best;
        __syncthreads();
        if (t == 0){
            const u64 b = umax64(umax64(wk[0], wk[1]), umax64(wk[2], wk[3]));
            bestv_s = keyv(b);
        }
        __syncthreads();
        const int bv = bestv_s;
        if (t < 128)
            *(float4*)(out + (long)row * DIM + t * 4) =
                *(const float4*)(w + (long)bv * DIM + t * 4);
    }
}

// ---- fallback: round-1 fp32 kernel (self-contained, no ws) ----
__launch_bounds__(256)
__global__ void fallback_full(const float* __restrict__ x, const float* __restrict__ w,
                              float* __restrict__ out){
    __shared__ __align__(16) float As[16][68];
    __shared__ __align__(16) float Bs[16][VOCAB];
    __shared__ int   idx_sf[64];
    __shared__ float c_s[VOCAB];

    const int t  = threadIdx.x;
    const int tx = t & 31;
    const int ty = t >> 5;
    const long rbase = (long)blockIdx.x * 64;
    const float* xblk = x + rbase * DIM;

    for (int vv = t; vv < VOCAB; vv += 256){
        double s = 0.0;
        for (int i = 0; i < DIM; ++i){
            const float wvv = w[i * VOCAB + vv];
            s += (double)wvv * (double)wvv;
        }
        c_s[vv] = (float)s;
    }

    float acc[8][16];
    #pragma unroll
    for (int r = 0; r < 8; ++r)
        #pragma unroll
        for (int j = 0; j < 16; ++j) acc[r][j] = 0.0f;

    for (int k0 = 0; k0 < DIM; k0 += 16){
        __syncthreads();
        {
            const int r  = t >> 2;
            const int kq = (t & 3) << 2;
            const float4 a4 = *(const float4*)(xblk + (long)r * DIM + k0 + kq);
            As[kq + 0][r] = a4.x; As[kq + 1][r] = a4.y;
            As[kq + 2][r] = a4.z; As[kq + 3][r] = a4.w;
        }
        #pragma unroll
        for (int vb = 0; vb < 8; ++vb){
            const int v  = (t >> 2) + (vb << 6);
            const int kq = (t & 3) << 2;
            const float4 b4 = *(const float4*)(w + (long)v * DIM + k0 + kq);
            Bs[kq + 0][v] = b4.x; Bs[kq + 1][v] = b4.y;
            Bs[kq + 2][v] = b4.z; Bs[kq + 3][v] = b4.w;
        }
        __syncthreads();

        #pragma unroll
        for (int k = 0; k < 16; ++k){
            float a[8];
            const float4 a03 = *(const float4*)&As[k][ty * 8];
            const float4 a47 = *(const float4*)&As[k][ty * 8 + 4];
            a[0] = a03.x; a[1] = a03.y; a[2] = a03.z; a[3] = a03.w;
            a[4] = a47.x; a[5] = a47.y; a[6] = a47.z; a[7] = a47.w;
            float b[16];
            #pragma unroll
            for (int j = 0; j < 16; ++j) b[j] = Bs[k][tx + (j << 5)];
            #pragma unroll
            for (int r = 0; r < 8; ++r)
                #pragma unroll
                for (int j = 0; j < 16; ++j)
                    acc[r][j] = fmaf(a[r], b[j], acc[r][j]);
        }
    }

    #pragma unroll
    for (int r = 0; r < 8; ++r){
        float best = acc[r][0] - 0.5f * c_s[tx];
        int   bv   = tx;
        #pragma unroll
        for (int j = 1; j < 16; ++j){
            const float s = acc[r][j] - 0.5f * c_s[tx + (j << 5)];
            if (s > best){ best = s; bv = tx + (j << 5); }
        }
        unsigned u = __float_as_uint(best);
        u = (u & 0x80000000u) ? ~u : (u | 0x80000000u);
        u64 key = ((u64)u << 32) | (unsigned)(~(unsigned)bv);
        #pragma unroll
        for (int m = 1; m <= 16; m <<= 1){
            const u64 o = __shfl_xor(key, m, 64);
            if (o > key) key = o;
        }
        if (tx == 0) idx_sf[ty * 8 + r] = (int)(~(unsigned)(key & 0xFFFFFFFFull));
    }
    __syncthreads();

    for (int rr = 0; rr < 64; rr += 2){
        const int row  = rr + (t >> 7);
        const int col  = (t & 127) << 2;
        const int vidx = idx_sf[row];
        const float4 val = *(const float4*)(w + (long)vidx * DIM + col);
        *(float4*)(out + (rbase + row) * DIM + col) = val;
    }
}

extern "C" void kernel_launch(void* const* d_in, const int* in_sizes, int n_in,
                              void* d_out, int out_size, void* d_ws, size_t ws_size,
                              hipStream_t stream){
    const float* x = (const float*)d_in[0];
    const float* w = (const float*)d_in[1];
    float* out = (float*)d_out;
    const int rows = in_sizes[0] / DIM;        // 65536

    // ws layout (bytes)
    const size_t whc_off  = 0;
    const size_t wlc_off  = whc_off + (size_t)DIM * VOCAB * 2;   // 512KB
    const size_t c_off    = wlc_off + (size_t)DIM * VOCAB * 2;   // +512KB
    const size_t list_off = c_off   + (size_t)VOCAB * 4;
    const size_t cnt_off  = list_off + (size_t)rows * 4;
    const size_t need     = cnt_off + 16;

    if (ws_size >= need){
        unsigned short* whc = (unsigned short*)((char*)d_ws + whc_off);
        unsigned short* wlc = (unsigned short*)((char*)d_ws + wlc_off);
        float*    c    = (float*)((char*)d_ws + c_off);
        int*      list = (int*)((char*)d_ws + list_off);
        unsigned* cnt  = (unsigned*)((char*)d_ws + cnt_off);

        prep_w<<<(DIM * VOCAB) / 256, 256, 0, stream>>>(w, whc, wlc, cnt);
        colsumsq_kernel<<<VOCAB, 64, 0, stream>>>(w, c);
        k1_scores<<<rows / 64, 256, 0, stream>>>(x, whc, wlc, c, w, out, list, cnt);
        refine_rows<<<512, 256, 0, stream>>>(x, w, c, list, cnt, out);
    } else {
        fallback_full<<<rows / 64, 256, 0, stream>>>(x, w, out);
    }
}